// Round 6
// baseline (88.190 us; speedup 1.0000x reference)
//
#include <hip/hip_runtime.h>
#include <hip/hip_bf16.h>
#include <math.h>

// Problem constants: T=4096, B=64, D=64, SCALE = 1/8.
#define T_DIM 4096
#define B_DIM 64
#define D_DIM 64
#define NROWS (T_DIM * B_DIM)   // 262144 rows (r = t*64+b), each 64 floats
#define NTILES (NROWS / 16)     // 16384 16-row MFMA tiles

// Workspace layout (float offsets)
#define WS_MBF   0        // 64x64 bf16 (2048 f): M[d][d'] fragment-ready
#define WS_VBF   2048     // 64x64 bf16: Wv[c][k]
#define WS_U     4096     // 64 f32: u[d'] = sum_o bq[o]*Wk[o,d']
#define WS_W     4160     // 64 f32: w[d]  = sum_o Wq[o,d]*bk[o]
#define WS_C     4224     // 1 f32:  c     = bq.bk
#define WS_MX    4240     // 64 f32: per-b max
#define WS_INV   4304     // 64 f32: per-b 1/sum
#define WS_PART  4368     // 512*2 f32: per-(b,chunk) online (m,s)
#define WS_SCORE 8192     // [NROWS] scores in natural r order

typedef __attribute__((ext_vector_type(4))) float f32x4;
typedef __attribute__((ext_vector_type(8))) short bf16x8;

static __device__ inline short f2bf(float x) {
  __hip_bfloat16 h = __float2bfloat16(x);
  return *reinterpret_cast<short*>(&h);
}

static __device__ inline bf16x8 cvt8(const float4 a, const float4 b) {
  bf16x8 r;
  r[0] = f2bf(a.x); r[1] = f2bf(a.y); r[2] = f2bf(a.z); r[3] = f2bf(a.w);
  r[4] = f2bf(b.x); r[5] = f2bf(b.y); r[6] = f2bf(b.z); r[7] = f2bf(b.w);
  return r;
}

static __device__ inline float dot4(const float4 a, const float4 b, float acc) {
  acc = fmaf(a.x, b.x, acc); acc = fmaf(a.y, b.y, acc);
  acc = fmaf(a.z, b.z, acc); acc = fmaf(a.w, b.w, acc);
  return acc;
}

// ---------------------------------------------------------------------------
// K1: bilinear constants; M and Wv stored bf16 fragment-ready; u,w,c f32.
__global__ __launch_bounds__(64) void k1_precompute(
    const float* __restrict__ Wq, const float* __restrict__ bq,
    const float* __restrict__ Wk, const float* __restrict__ bk,
    const float* __restrict__ Wv, float* __restrict__ ws) {
  const int tid = threadIdx.x;
  const int blk = blockIdx.x;
  unsigned short* __restrict__ mbf = (unsigned short*)(ws + WS_MBF);
  unsigned short* __restrict__ vbf = (unsigned short*)(ws + WS_VBF);
  if (blk < 64) {
    const int d = blk;
    float acc = 0.f;
#pragma unroll
    for (int o = 0; o < 64; ++o)
      acc = fmaf(Wq[o * 64 + d], Wk[o * 64 + tid], acc);
    mbf[d * 64 + tid] = (unsigned short)f2bf(acc);
    vbf[d * 64 + tid] = (unsigned short)f2bf(Wv[d * 64 + tid]);
  } else {
    float uacc = 0.f, wacc = 0.f, cacc = 0.f;
#pragma unroll
    for (int o = 0; o < 64; ++o) {
      uacc = fmaf(bq[o], Wk[o * 64 + tid], uacc);
      wacc = fmaf(Wq[o * 64 + tid], bk[o], wacc);
      cacc = fmaf(bq[o], bk[o], cacc);
    }
    ws[WS_U + tid] = uacc;
    ws[WS_W + tid] = wacc;
    if (tid == 0) ws[WS_C] = cacc;
  }
}

// ---------------------------------------------------------------------------
// K2: score[r] = 0.125*(e^T M f + w.e + u.f + c). Transposed MFMA (H^T =
// M x F^T). ALL loads issued before a sched_barrier(0), so every VMEM op is
// in flight simultaneously (one latency exposure, not eight).
__global__ __launch_bounds__(256, 2) void k2_score_mfma(
    const float* __restrict__ eeg, const float* __restrict__ fnirs,
    const unsigned short* __restrict__ mbf, const float* __restrict__ wvec,
    const float* __restrict__ uvec, const float* __restrict__ cvec,
    float* __restrict__ score) {
  const int lane = threadIdx.x & 63;
  const int wv   = threadIdx.x >> 6;
  const int tile = blockIdx.x * 4 + wv;
  const int col  = lane & 15;    // row r within tile
  const int grp  = lane >> 4;    // k-group / d-quad
  const int kb   = grp * 8;
  const int rbase = tile * 16;

  // ---------------- load phase: issue everything ----------------
  const float* fa = fnirs + (size_t)(rbase + col) * 64 + kb;
  const float4 f0a = *reinterpret_cast<const float4*>(fa);
  const float4 f0b = *reinterpret_cast<const float4*>(fa + 4);
  const float4 f1a = *reinterpret_cast<const float4*>(fa + 32);
  const float4 f1b = *reinterpret_cast<const float4*>(fa + 36);
  const float* ea = eeg + (size_t)(rbase + col) * 64 + grp * 4;
  const float4 ef0 = *reinterpret_cast<const float4*>(ea);
  const float4 ef1 = *reinterpret_cast<const float4*>(ea + 16);
  const float4 ef2 = *reinterpret_cast<const float4*>(ea + 32);
  const float4 ef3 = *reinterpret_cast<const float4*>(ea + 48);
  bf16x8 bm[4][2];
#pragma unroll
  for (int dt = 0; dt < 4; ++dt)
#pragma unroll
    for (int kf = 0; kf < 2; ++kf)
      bm[dt][kf] = *reinterpret_cast<const bf16x8*>(
          mbf + (dt * 16 + col) * 64 + kf * 32 + kb);
  const float4 wf0 = *reinterpret_cast<const float4*>(wvec + 0  + grp * 4);
  const float4 wf1 = *reinterpret_cast<const float4*>(wvec + 16 + grp * 4);
  const float4 wf2 = *reinterpret_cast<const float4*>(wvec + 32 + grp * 4);
  const float4 wf3 = *reinterpret_cast<const float4*>(wvec + 48 + grp * 4);
  const float4 u0a = *reinterpret_cast<const float4*>(uvec + kb);
  const float4 u0b = *reinterpret_cast<const float4*>(uvec + kb + 4);
  const float4 u1a = *reinterpret_cast<const float4*>(uvec + kb + 32);
  const float4 u1b = *reinterpret_cast<const float4*>(uvec + kb + 36);
  const float cb = cvec[0];
  __builtin_amdgcn_sched_barrier(0);   // keep all loads above, live

  // ---------------- compute phase ----------------
  float s = 0.f;
  s = dot4(f0a, u0a, s); s = dot4(f0b, u0b, s);
  s = dot4(f1a, u1a, s); s = dot4(f1b, u1b, s);

  const bf16x8 a0 = cvt8(f0a, f0b);
  const bf16x8 a1 = cvt8(f1a, f1b);
  const f32x4 zero = {0.f, 0.f, 0.f, 0.f};
  f32x4 acc[4];
#pragma unroll
  for (int dt = 0; dt < 4; ++dt) {
    acc[dt] = __builtin_amdgcn_mfma_f32_16x16x32_bf16(bm[dt][0], a0, zero, 0, 0, 0);
    acc[dt] = __builtin_amdgcn_mfma_f32_16x16x32_bf16(bm[dt][1], a1, acc[dt], 0, 0, 0);
  }

  float4 h;
  h.x = acc[0][0] + wf0.x; h.y = acc[0][1] + wf0.y; h.z = acc[0][2] + wf0.z; h.w = acc[0][3] + wf0.w;
  s = dot4(ef0, h, s);
  h.x = acc[1][0] + wf1.x; h.y = acc[1][1] + wf1.y; h.z = acc[1][2] + wf1.z; h.w = acc[1][3] + wf1.w;
  s = dot4(ef1, h, s);
  h.x = acc[2][0] + wf2.x; h.y = acc[2][1] + wf2.y; h.z = acc[2][2] + wf2.z; h.w = acc[2][3] + wf2.w;
  s = dot4(ef2, h, s);
  h.x = acc[3][0] + wf3.x; h.y = acc[3][1] + wf3.y; h.z = acc[3][2] + wf3.z; h.w = acc[3][3] + wf3.w;
  s = dot4(ef3, h, s);

  s += __shfl_xor(s, 16, 64);
  s += __shfl_xor(s, 32, 64);
  if (lane < 16)
    score[rbase + lane] = (s + cb) * 0.125f;
}

// ---------------------------------------------------------------------------
// K3a: per-(b, 512-t-chunk) online softmax partials (m, s). 512 blocks.
__global__ __launch_bounds__(256) void k3a_partial(
    const float* __restrict__ sc, float* __restrict__ part) {
  __shared__ float lm[4], ls[4];
  const int bi = blockIdx.x;
  const int b  = bi >> 3;
  const int ck = bi & 7;
  const int tid = threadIdx.x;
  const int t0 = ck * 512;

  const float v1 = sc[(size_t)(t0 + tid) * 64 + b];
  const float v2 = sc[(size_t)(t0 + 256 + tid) * 64 + b];
  float m = fmaxf(v1, v2);
  float s = __expf(v1 - m) + __expf(v2 - m);
#pragma unroll
  for (int off = 32; off > 0; off >>= 1) {
    const float mo = __shfl_xor(m, off, 64);
    const float so = __shfl_xor(s, off, 64);
    const float mn = fmaxf(m, mo);
    s = s * __expf(m - mn) + so * __expf(mo - mn);
    m = mn;
  }
  if ((tid & 63) == 0) { lm[tid >> 6] = m; ls[tid >> 6] = s; }
  __syncthreads();
  if (tid == 0) {
    float M = lm[0], S = ls[0];
#pragma unroll
    for (int w = 1; w < 4; ++w) {
      const float Mn = fmaxf(M, lm[w]);
      S = S * __expf(M - Mn) + ls[w] * __expf(lm[w] - Mn);
      M = Mn;
    }
    part[bi * 2] = M;
    part[bi * 2 + 1] = S;
  }
}

// K3b: combine 8 partials per b -> m[b], inv[b]. One tiny block.
__global__ __launch_bounds__(64) void k3b_combine(
    const float* __restrict__ part, float* __restrict__ mx,
    float* __restrict__ inv) {
  const int b = threadIdx.x;
  float M = part[(b * 8) * 2], S = part[(b * 8) * 2 + 1];
#pragma unroll
  for (int ck = 1; ck < 8; ++ck) {
    const float m2 = part[(b * 8 + ck) * 2];
    const float s2 = part[(b * 8 + ck) * 2 + 1];
    const float Mn = fmaxf(M, m2);
    S = S * __expf(M - Mn) + s2 * __expf(m2 - Mn);
    M = Mn;
  }
  mx[b] = M;
  inv[b] = 1.0f / S;
}

// ---------------------------------------------------------------------------
// K4: out = eeg + attn*(Wv f + bv); attn inline from score,m,inv.
// Same load-phase / sched_barrier / compute-phase split.
__global__ __launch_bounds__(256, 2) void k4_output_mfma(
    const float* __restrict__ eeg, const float* __restrict__ fnirs,
    const unsigned short* __restrict__ vbf, const float* __restrict__ bv,
    const float* __restrict__ score, const float* __restrict__ mx,
    const float* __restrict__ inv, float* __restrict__ out) {
  const int lane = threadIdx.x & 63;
  const int wv   = threadIdx.x >> 6;
  const int tile = blockIdx.x * 4 + wv;
  const int col  = lane & 15;
  const int grp  = lane >> 4;
  const int kb   = grp * 8;
  const int rbase = tile * 16;
  const int r = rbase + col;
  const int b = r & 63;

  // ---------------- load phase ----------------
  const float* fa = fnirs + (size_t)r * 64 + kb;
  const float4 f0a = *reinterpret_cast<const float4*>(fa);
  const float4 f0b = *reinterpret_cast<const float4*>(fa + 4);
  const float4 f1a = *reinterpret_cast<const float4*>(fa + 32);
  const float4 f1b = *reinterpret_cast<const float4*>(fa + 36);
  const float* ea = eeg + (size_t)r * 64 + grp * 4;
  const float4 ef0 = *reinterpret_cast<const float4*>(ea);
  const float4 ef1 = *reinterpret_cast<const float4*>(ea + 16);
  const float4 ef2 = *reinterpret_cast<const float4*>(ea + 32);
  const float4 ef3 = *reinterpret_cast<const float4*>(ea + 48);
  const float sc_r = score[r];
  const float mx_b = mx[b];
  const float inv_b = inv[b];
  bf16x8 bm[4][2];
#pragma unroll
  for (int dt = 0; dt < 4; ++dt)
#pragma unroll
    for (int kf = 0; kf < 2; ++kf)
      bm[dt][kf] = *reinterpret_cast<const bf16x8*>(
          vbf + (dt * 16 + col) * 64 + kf * 32 + kb);
  const float4 bv0 = *reinterpret_cast<const float4*>(bv + 0  + grp * 4);
  const float4 bv1 = *reinterpret_cast<const float4*>(bv + 16 + grp * 4);
  const float4 bv2 = *reinterpret_cast<const float4*>(bv + 32 + grp * 4);
  const float4 bv3 = *reinterpret_cast<const float4*>(bv + 48 + grp * 4);
  __builtin_amdgcn_sched_barrier(0);

  // ---------------- compute phase ----------------
  const float a = __expf(sc_r - mx_b) * inv_b;
  const bf16x8 a0 = cvt8(f0a, f0b);
  const bf16x8 a1 = cvt8(f1a, f1b);
  const f32x4 zero = {0.f, 0.f, 0.f, 0.f};
  f32x4 acc[4];
#pragma unroll
  for (int dt = 0; dt < 4; ++dt) {
    acc[dt] = __builtin_amdgcn_mfma_f32_16x16x32_bf16(bm[dt][0], a0, zero, 0, 0, 0);
    acc[dt] = __builtin_amdgcn_mfma_f32_16x16x32_bf16(bm[dt][1], a1, acc[dt], 0, 0, 0);
  }

  float* oa = out + (size_t)r * 64 + grp * 4;
  float4 o;
  o.x = fmaf(a, acc[0][0] + bv0.x, ef0.x); o.y = fmaf(a, acc[0][1] + bv0.y, ef0.y);
  o.z = fmaf(a, acc[0][2] + bv0.z, ef0.z); o.w = fmaf(a, acc[0][3] + bv0.w, ef0.w);
  *reinterpret_cast<float4*>(oa) = o;
  o.x = fmaf(a, acc[1][0] + bv1.x, ef1.x); o.y = fmaf(a, acc[1][1] + bv1.y, ef1.y);
  o.z = fmaf(a, acc[1][2] + bv1.z, ef1.z); o.w = fmaf(a, acc[1][3] + bv1.w, ef1.w);
  *reinterpret_cast<float4*>(oa + 16) = o;
  o.x = fmaf(a, acc[2][0] + bv2.x, ef2.x); o.y = fmaf(a, acc[2][1] + bv2.y, ef2.y);
  o.z = fmaf(a, acc[2][2] + bv2.z, ef2.z); o.w = fmaf(a, acc[2][3] + bv2.w, ef2.w);
  *reinterpret_cast<float4*>(oa + 32) = o;
  o.x = fmaf(a, acc[3][0] + bv3.x, ef3.x); o.y = fmaf(a, acc[3][1] + bv3.y, ef3.y);
  o.z = fmaf(a, acc[3][2] + bv3.z, ef3.z); o.w = fmaf(a, acc[3][3] + bv3.w, ef3.w);
  *reinterpret_cast<float4*>(oa + 48) = o;
}

// ---------------------------------------------------------------------------
extern "C" void kernel_launch(void* const* d_in, const int* in_sizes, int n_in,
                              void* d_out, int out_size, void* d_ws, size_t ws_size,
                              hipStream_t stream) {
  const float* eeg   = (const float*)d_in[0];
  const float* fnirs = (const float*)d_in[1];
  const float* Wq    = (const float*)d_in[2];
  const float* bq    = (const float*)d_in[3];
  const float* Wk    = (const float*)d_in[4];
  const float* bk    = (const float*)d_in[5];
  const float* Wv    = (const float*)d_in[6];
  const float* bv    = (const float*)d_in[7];
  float* out = (float*)d_out;
  float* ws  = (float*)d_ws;

  k1_precompute<<<65, 64, 0, stream>>>(Wq, bq, Wk, bk, Wv, ws);
  k2_score_mfma<<<NTILES / 4, 256, 0, stream>>>(
      eeg, fnirs, (const unsigned short*)(ws + WS_MBF), ws + WS_W,
      ws + WS_U, ws + WS_C, ws + WS_SCORE);
  k3a_partial<<<512, 256, 0, stream>>>(ws + WS_SCORE, ws + WS_PART);
  k3b_combine<<<1, 64, 0, stream>>>(ws + WS_PART, ws + WS_MX, ws + WS_INV);
  k4_output_mfma<<<NTILES / 4, 256, 0, stream>>>(
      eeg, fnirs, (const unsigned short*)(ws + WS_VBF), bv,
      ws + WS_SCORE, ws + WS_MX, ws + WS_INV, out);
}

// Round 7
// 66.536 us; speedup vs baseline: 1.3254x; 1.3254x over previous
//
#include <hip/hip_runtime.h>
#include <hip/hip_bf16.h>
#include <math.h>

// Problem constants: T=4096, B=64, D=64, SCALE = 1/8.
#define T_DIM 4096
#define B_DIM 64
#define NROWS (T_DIM * B_DIM)   // 262144 rows (r = t*64+b), 64 floats each
#define NTILES (NROWS / 16)     // 16384 16-row MFMA tiles

// Workspace layout (float offsets)
#define WS_MFRAG 0        // 4096 u16 (2048 f): M fragment-linear bf16
#define WS_VFRAG 2048     // 4096 u16: Wv fragment-linear bf16
#define WS_U     4096     // 64 f32: u[k] = sum_o bq[o]*Wk[o,k]
#define WS_W     4160     // 64 f32: w[d] = sum_o Wq[o,d]*bk[o]
#define WS_C     4224     // 1 f32:  c = bq.bk
#define WS_MX    4240     // 64 f32: per-b max
#define WS_INV   4304     // 64 f32: per-b 1/sum
#define WS_PM    4368     // 64x64 f32: partial max  [ck*64+b]
#define WS_PS    8464     // 64x64 f32: partial sum
#define WS_SCORE 16384    // [NROWS] scores, natural r order

typedef __attribute__((ext_vector_type(4))) float f32x4;
typedef __attribute__((ext_vector_type(8))) short bf16x8;

static __device__ inline short f2bf(float x) {
  __hip_bfloat16 h = __float2bfloat16(x);
  return *reinterpret_cast<short*>(&h);
}

static __device__ inline bf16x8 cvt8(const float4 a, const float4 b) {
  bf16x8 r;
  r[0] = f2bf(a.x); r[1] = f2bf(a.y); r[2] = f2bf(a.z); r[3] = f2bf(a.w);
  r[4] = f2bf(b.x); r[5] = f2bf(b.y); r[6] = f2bf(b.z); r[7] = f2bf(b.w);
  return r;
}

static __device__ inline float dot4(const float4 a, const float4 b, float acc) {
  acc = fmaf(a.x, b.x, acc); acc = fmaf(a.y, b.y, acc);
  acc = fmaf(a.z, b.z, acc); acc = fmaf(a.w, b.w, acc);
  return acc;
}

// Fragment-linear index (u16 units) for weight element W[d][k]:
// frag (dt=d>>4, kf=k>>5) stored as 64 lanes x 8 elems contiguous.
static __device__ __host__ inline int frag_idx(int d, int k) {
  return ((d >> 4) * 2 + (k >> 5)) * 512 +
         ((((k >> 3) & 3) * 16 + (d & 15)) * 8) + (k & 7);
}

// ---------------------------------------------------------------------------
// K1: bilinear constants; M and Wv stored bf16 FRAGMENT-LINEAR (1KB-contig
// per fragment load in k2/k4); u,w,c f32.
__global__ __launch_bounds__(64) void k1_precompute(
    const float* __restrict__ Wq, const float* __restrict__ bq,
    const float* __restrict__ Wk, const float* __restrict__ bk,
    const float* __restrict__ Wv, float* __restrict__ ws) {
  const int tid = threadIdx.x;
  const int blk = blockIdx.x;
  unsigned short* __restrict__ mfrag = (unsigned short*)(ws + WS_MFRAG);
  unsigned short* __restrict__ vfrag = (unsigned short*)(ws + WS_VFRAG);
  if (blk < 64) {
    const int d = blk;
    float acc = 0.f;
#pragma unroll
    for (int o = 0; o < 64; ++o)
      acc = fmaf(Wq[o * 64 + d], Wk[o * 64 + tid], acc);
    const int idx = frag_idx(d, tid);
    mfrag[idx] = (unsigned short)f2bf(acc);
    vfrag[idx] = (unsigned short)f2bf(Wv[d * 64 + tid]);
  } else {
    float uacc = 0.f, wacc = 0.f, cacc = 0.f;
#pragma unroll
    for (int o = 0; o < 64; ++o) {
      uacc = fmaf(bq[o], Wk[o * 64 + tid], uacc);
      wacc = fmaf(Wq[o * 64 + tid], bk[o], wacc);
      cacc = fmaf(bq[o], bk[o], cacc);
    }
    ws[WS_U + tid] = uacc;
    ws[WS_W + tid] = wacc;
    if (tid == 0) ws[WS_C] = cacc;
  }
}

// ---------------------------------------------------------------------------
// K2: score[r] = 0.125*(e^T M f + w.e + u.f + c).
// All global loads contiguous-1KB; F staged through wave-private swizzled
// LDS to fragment layout; Hp staged back to linear for the epilogue.
__global__ __launch_bounds__(256, 2) void k2_score_mfma(
    const float* __restrict__ eeg, const float* __restrict__ fnirs,
    const unsigned short* __restrict__ mfrag, const float* __restrict__ wvec,
    const float* __restrict__ uvec, const float* __restrict__ cvec,
    float* __restrict__ score) {
  __shared__ float lds[4][1024];
  const int tid = threadIdx.x;
  const int lane = tid & 63;
  const int wv = tid >> 6;
  const int tile = blockIdx.x * 4 + wv;
  const int c = lane & 15;
  const int g = lane >> 4;
  const int rbase = tile * 16;
  float* L = lds[wv];

  // ---- global load phase: every load is a contiguous 1KB wave access ----
  const float* Fb = fnirs + (size_t)rbase * 64;
  const float* Eb = eeg + (size_t)rbase * 64;
  float4 Fj[4], Ej[4];
#pragma unroll
  for (int j = 0; j < 4; ++j)
    Fj[j] = *reinterpret_cast<const float4*>(Fb + j * 256 + lane * 4);
#pragma unroll
  for (int j = 0; j < 4; ++j)
    Ej[j] = *reinterpret_cast<const float4*>(Eb + j * 256 + lane * 4);
  bf16x8 bm[4][2];
#pragma unroll
  for (int dt = 0; dt < 4; ++dt)
#pragma unroll
    for (int kf = 0; kf < 2; ++kf)
      bm[dt][kf] = *reinterpret_cast<const bf16x8*>(
          mfrag + (((dt * 2 + kf) << 9) + lane * 8));
  float4 wf[4];
#pragma unroll
  for (int dt = 0; dt < 4; ++dt)
    wf[dt] = *reinterpret_cast<const float4*>(wvec + dt * 16 + g * 4);
  const float4 u4 = *reinterpret_cast<const float4*>(uvec + c * 4);
  const float cb = cvec[0];
  __builtin_amdgcn_sched_barrier(0);

  // u.f partials in linear layout (lane: row j*4+g, d-chunk c*4..+4)
  float uf[4];
#pragma unroll
  for (int j = 0; j < 4; ++j) uf[j] = dot4(Fj[j], u4, 0.f);

  // stage F -> LDS, XOR-swizzled (chunk ^= row&7; chunk = 8 floats)
#pragma unroll
  for (int j = 0; j < 4; ++j) {
    const int r = j * 4 + g;
    const int addr = r * 64 + ((((c >> 1) ^ (r & 7)) << 3) + ((c & 1) << 2));
    *reinterpret_cast<float4*>(&L[addr]) = Fj[j];
  }
  // read F in fragment layout: lane (c,g) row c, k = h*32 + g*8 .. +8
  const int fr0 = c * 64 + (((g) ^ (c & 7)) << 3);
  const int fr1 = c * 64 + (((4 + g) ^ (c & 7)) << 3);
  const float4 p00 = *reinterpret_cast<const float4*>(&L[fr0]);
  const float4 p01 = *reinterpret_cast<const float4*>(&L[fr0 + 4]);
  const float4 p10 = *reinterpret_cast<const float4*>(&L[fr1]);
  const float4 p11 = *reinterpret_cast<const float4*>(&L[fr1 + 4]);
  const bf16x8 a0 = cvt8(p00, p01);
  const bf16x8 a1 = cvt8(p10, p11);

  const f32x4 zero = {0.f, 0.f, 0.f, 0.f};
  f32x4 acc[4];
#pragma unroll
  for (int dt = 0; dt < 4; ++dt) {
    acc[dt] = __builtin_amdgcn_mfma_f32_16x16x32_bf16(bm[dt][0], a0, zero, 0, 0, 0);
    acc[dt] = __builtin_amdgcn_mfma_f32_16x16x32_bf16(bm[dt][1], a1, acc[dt], 0, 0, 0);
  }

  // Hp = acc + w, staged C-layout -> LDS (reuse same slice; in-wave DS order)
#pragma unroll
  for (int dt = 0; dt < 4; ++dt) {
    float4 hp;
    hp.x = acc[dt][0] + wf[dt].x; hp.y = acc[dt][1] + wf[dt].y;
    hp.z = acc[dt][2] + wf[dt].z; hp.w = acc[dt][3] + wf[dt].w;
    const int ch = dt * 2 + (g >> 1);
    const int addr = c * 64 + (((ch ^ (c & 7)) << 3) + ((g & 1) << 2));
    *reinterpret_cast<float4*>(&L[addr]) = hp;
  }
  // linear epilogue: p = E.(Hp) + u.f; reduce over the 16 c-lanes
#pragma unroll
  for (int j = 0; j < 4; ++j) {
    const int r = j * 4 + g;
    const int addr = r * 64 + ((((c >> 1) ^ (r & 7)) << 3) + ((c & 1) << 2));
    const float4 hp = *reinterpret_cast<const float4*>(&L[addr]);
    float p = dot4(Ej[j], hp, uf[j]);
    p += __shfl_xor(p, 1, 64);
    p += __shfl_xor(p, 2, 64);
    p += __shfl_xor(p, 4, 64);
    p += __shfl_xor(p, 8, 64);
    if (c == 0) score[rbase + j * 4 + g] = (p + cb) * 0.125f;
  }
}

// ---------------------------------------------------------------------------
// K3a: per-(64-t-chunk) online (m,s) for ALL b. lane = b -> coalesced reads.
__global__ __launch_bounds__(256) void k3a_partial(
    const float* __restrict__ sc, float* __restrict__ pm,
    float* __restrict__ ps) {
  __shared__ float sm[4][64], ss[4][64];
  const int tid = threadIdx.x;
  const int b = tid & 63;
  const int tq = tid >> 6;
  const int t0 = blockIdx.x * 64;
  float m = -1e30f, s = 0.f;
#pragma unroll
  for (int k = 0; k < 16; ++k) {
    const float v = sc[(size_t)(t0 + k * 4 + tq) * 64 + b];
    const float mn = fmaxf(m, v);
    s = s * __expf(m - mn) + __expf(v - mn);
    m = mn;
  }
  sm[tq][b] = m; ss[tq][b] = s;
  __syncthreads();
  if (tid < 64) {
    float M = sm[0][b], S = ss[0][b];
#pragma unroll
    for (int w = 1; w < 4; ++w) {
      const float m2 = sm[w][b], s2 = ss[w][b];
      const float Mn = fmaxf(M, m2);
      S = S * __expf(M - Mn) + s2 * __expf(m2 - Mn);
      M = Mn;
    }
    pm[blockIdx.x * 64 + b] = M;
    ps[blockIdx.x * 64 + b] = S;
  }
}

// K3b: combine 64 chunk-partials per b. One block.
__global__ __launch_bounds__(64) void k3b_combine(
    const float* __restrict__ pm, const float* __restrict__ ps,
    float* __restrict__ mx, float* __restrict__ inv) {
  const int b = threadIdx.x;
  float M = pm[b], S = ps[b];
#pragma unroll
  for (int ck = 1; ck < 64; ++ck) {
    const float m2 = pm[ck * 64 + b], s2 = ps[ck * 64 + b];
    const float Mn = fmaxf(M, m2);
    S = S * __expf(M - Mn) + s2 * __expf(m2 - Mn);
    M = Mn;
  }
  mx[b] = M;
  inv[b] = 1.0f / S;
}

// ---------------------------------------------------------------------------
// K4: out = eeg + attn*(Wv f + bv). Same staging discipline; stores are
// contiguous 1KB (V staged C-layout -> linear with attn already folded).
__global__ __launch_bounds__(256, 2) void k4_output_mfma(
    const float* __restrict__ eeg, const float* __restrict__ fnirs,
    const unsigned short* __restrict__ vfrag, const float* __restrict__ bv,
    const float* __restrict__ score, const float* __restrict__ mx,
    const float* __restrict__ inv, float* __restrict__ out) {
  __shared__ float lds[4][1024];
  const int tid = threadIdx.x;
  const int lane = tid & 63;
  const int wv = tid >> 6;
  const int tile = blockIdx.x * 4 + wv;
  const int c = lane & 15;
  const int g = lane >> 4;
  const int rbase = tile * 16;
  float* L = lds[wv];

  // ---- global load phase ----
  const float* Fb = fnirs + (size_t)rbase * 64;
  const float* Eb = eeg + (size_t)rbase * 64;
  float4 Fj[4], Ej[4];
#pragma unroll
  for (int j = 0; j < 4; ++j)
    Fj[j] = *reinterpret_cast<const float4*>(Fb + j * 256 + lane * 4);
#pragma unroll
  for (int j = 0; j < 4; ++j)
    Ej[j] = *reinterpret_cast<const float4*>(Eb + j * 256 + lane * 4);
  bf16x8 bm[4][2];
#pragma unroll
  for (int dt = 0; dt < 4; ++dt)
#pragma unroll
    for (int kf = 0; kf < 2; ++kf)
      bm[dt][kf] = *reinterpret_cast<const bf16x8*>(
          vfrag + (((dt * 2 + kf) << 9) + lane * 8));
  float4 bvf[4];
#pragma unroll
  for (int dt = 0; dt < 4; ++dt)
    bvf[dt] = *reinterpret_cast<const float4*>(bv + dt * 16 + g * 4);
  const float scr = score[rbase + c];
  const int bidx = (rbase + c) & 63;
  const float mxv = mx[bidx];
  const float invv = inv[bidx];
  __builtin_amdgcn_sched_barrier(0);

  // stage F -> LDS swizzled
#pragma unroll
  for (int j = 0; j < 4; ++j) {
    const int r = j * 4 + g;
    const int addr = r * 64 + ((((c >> 1) ^ (r & 7)) << 3) + ((c & 1) << 2));
    *reinterpret_cast<float4*>(&L[addr]) = Fj[j];
  }
  const int fr0 = c * 64 + (((g) ^ (c & 7)) << 3);
  const int fr1 = c * 64 + (((4 + g) ^ (c & 7)) << 3);
  const float4 p00 = *reinterpret_cast<const float4*>(&L[fr0]);
  const float4 p01 = *reinterpret_cast<const float4*>(&L[fr0 + 4]);
  const float4 p10 = *reinterpret_cast<const float4*>(&L[fr1]);
  const float4 p11 = *reinterpret_cast<const float4*>(&L[fr1 + 4]);
  const bf16x8 a0 = cvt8(p00, p01);
  const bf16x8 a1 = cvt8(p10, p11);

  const f32x4 zero = {0.f, 0.f, 0.f, 0.f};
  f32x4 acc[4];
#pragma unroll
  for (int dt = 0; dt < 4; ++dt) {
    acc[dt] = __builtin_amdgcn_mfma_f32_16x16x32_bf16(bm[dt][0], a0, zero, 0, 0, 0);
    acc[dt] = __builtin_amdgcn_mfma_f32_16x16x32_bf16(bm[dt][1], a1, acc[dt], 0, 0, 0);
  }

  // attn (per row c), fold into V, stage C-layout -> LDS
  const float aC = __expf(scr - mxv) * invv;
#pragma unroll
  for (int dt = 0; dt < 4; ++dt) {
    float4 v4;
    v4.x = aC * (acc[dt][0] + bvf[dt].x); v4.y = aC * (acc[dt][1] + bvf[dt].y);
    v4.z = aC * (acc[dt][2] + bvf[dt].z); v4.w = aC * (acc[dt][3] + bvf[dt].w);
    const int ch = dt * 2 + (g >> 1);
    const int addr = c * 64 + (((ch ^ (c & 7)) << 3) + ((g & 1) << 2));
    *reinterpret_cast<float4*>(&L[addr]) = v4;
  }
  // linear epilogue: out = E + V (1KB-contiguous stores)
  float* Ob = out + (size_t)rbase * 64;
#pragma unroll
  for (int j = 0; j < 4; ++j) {
    const int r = j * 4 + g;
    const int addr = r * 64 + ((((c >> 1) ^ (r & 7)) << 3) + ((c & 1) << 2));
    const float4 v = *reinterpret_cast<const float4*>(&L[addr]);
    float4 o;
    o.x = Ej[j].x + v.x; o.y = Ej[j].y + v.y;
    o.z = Ej[j].z + v.z; o.w = Ej[j].w + v.w;
    *reinterpret_cast<float4*>(Ob + j * 256 + lane * 4) = o;
  }
}

// ---------------------------------------------------------------------------
extern "C" void kernel_launch(void* const* d_in, const int* in_sizes, int n_in,
                              void* d_out, int out_size, void* d_ws, size_t ws_size,
                              hipStream_t stream) {
  const float* eeg   = (const float*)d_in[0];
  const float* fnirs = (const float*)d_in[1];
  const float* Wq    = (const float*)d_in[2];
  const float* bq    = (const float*)d_in[3];
  const float* Wk    = (const float*)d_in[4];
  const float* bk    = (const float*)d_in[5];
  const float* Wv    = (const float*)d_in[6];
  const float* bv    = (const float*)d_in[7];
  float* out = (float*)d_out;
  float* ws  = (float*)d_ws;

  k1_precompute<<<65, 64, 0, stream>>>(Wq, bq, Wk, bk, Wv, ws);
  k2_score_mfma<<<NTILES / 4, 256, 0, stream>>>(
      eeg, fnirs, (const unsigned short*)(ws + WS_MFRAG), ws + WS_W,
      ws + WS_U, ws + WS_C, ws + WS_SCORE);
  k3a_partial<<<64, 256, 0, stream>>>(ws + WS_SCORE, ws + WS_PM, ws + WS_PS);
  k3b_combine<<<1, 64, 0, stream>>>(ws + WS_PM, ws + WS_PS,
                                    ws + WS_MX, ws + WS_INV);
  k4_output_mfma<<<NTILES / 4, 256, 0, stream>>>(
      eeg, fnirs, (const unsigned short*)(ws + WS_VFRAG), bv,
      ws + WS_SCORE, ws + WS_MX, ws + WS_INV, out);
}